// Round 2
// baseline (182.460 us; speedup 1.0000x reference)
//
#include <hip/hip_runtime.h>

#define HH 1024
#define WW 1024
#define NB 8
#define TY 8
#define NCC_BLOCKS (NB * (HH / TY))      // 1024
#define SROWS 16
#define SM_BLOCKS (NB * 2 * HH / SROWS)  // 1024
#define RW (1.0f / 81.0f)

// Vertical sliding accumulate: add/sub one row's element + products into the
// per-thread column sums. y is block-uniform -> uniform branch.
template <int SGN>
__device__ __forceinline__ void vrow(const float* __restrict__ Ib, const float* __restrict__ Jb,
                                     int y, int t,
                                     float vI[4], float vJ[4],
                                     float vI2[4], float vJ2[4], float vIJ[4]) {
    if (y < 0 || y >= HH) return;
    const float4 i4 = ((const float4*)(Ib + (size_t)y * WW))[t];
    const float4 j4 = ((const float4*)(Jb + (size_t)y * WW))[t];
    const float fi[4] = {i4.x, i4.y, i4.z, i4.w};
    const float fj[4] = {j4.x, j4.y, j4.z, j4.w};
#pragma unroll
    for (int c = 0; c < 4; ++c) {
        const float a = fi[c], b = fj[c];
        if (SGN > 0) {
            vI[c] += a; vJ[c] += b;
            vI2[c] = fmaf(a, a, vI2[c]);
            vJ2[c] = fmaf(b, b, vJ2[c]);
            vIJ[c] = fmaf(a, b, vIJ[c]);
        } else {
            vI[c] -= a; vJ[c] -= b;
            vI2[c] = fmaf(-a, a, vI2[c]);
            vJ2[c] = fmaf(-b, b, vJ2[c]);
            vIJ[c] = fmaf(-a, b, vIJ[c]);
        }
    }
}

// Horizontal 9-window sliding sum over column-sums: left/right neighbor from
// LDS (halo zeros at the image edges), own 4 from registers.
__device__ __forceinline__ void hslide(const float4 l, const float4 r, const float own[4], float hs[4]) {
    float h = l.x + l.y + l.z + l.w + own[0] + own[1] + own[2] + own[3] + r.x;
    hs[0] = h;
    h += r.y - l.x; hs[1] = h;
    h += r.z - l.y; hs[2] = h;
    h += r.w - l.z; hs[3] = h;
}

__global__ __launch_bounds__(256) void fused_kernel(const float* __restrict__ I,
                                                    const float* __restrict__ J,
                                                    const float* __restrict__ S,
                                                    float* __restrict__ ws) {
    __shared__ float4 cs[5][258];   // [quantity][thread+1], halos at 0 and 257
    __shared__ float red[8];
    const int bid = blockIdx.x;
    const int t = threadIdx.x;
    const int lane = t & 63;
    const int wid = t >> 6;

    if ((bid & 1) == 0) {
        // ---------------- NCC path ----------------
        const int nb = bid >> 1;          // [0, 1024)
        const int b = nb >> 7;            // image
        const int strip = nb & 127;       // row strip
        const int y0 = strip * TY;
        const float* Ib = I + (size_t)b * HH * WW;
        const float* Jb = J + (size_t)b * HH * WW;

        float vI[4] = {0, 0, 0, 0}, vJ[4] = {0, 0, 0, 0};
        float vI2[4] = {0, 0, 0, 0}, vJ2[4] = {0, 0, 0, 0}, vIJ[4] = {0, 0, 0, 0};
        float ccacc = 0.f;

        // zero the halo once (visible after the first in-loop barrier)
        if (t < 5) {
            cs[t][0] = float4{0, 0, 0, 0};
            cs[t][257] = float4{0, 0, 0, 0};
        }

        // warm-up: vertical sums of rows y0-4 .. y0+3
#pragma unroll
        for (int k = 0; k < 8; ++k)
            vrow<1>(Ib, Jb, y0 - 4 + k, t, vI, vJ, vI2, vJ2, vIJ);

#pragma unroll 2
        for (int k = 0; k < TY; ++k) {
            const int y = y0 + k;
            vrow<1>(Ib, Jb, y + 4, t, vI, vJ, vI2, vJ2, vIJ);

            cs[0][t + 1] = float4{vI[0], vI[1], vI[2], vI[3]};
            cs[1][t + 1] = float4{vJ[0], vJ[1], vJ[2], vJ[3]};
            cs[2][t + 1] = float4{vI2[0], vI2[1], vI2[2], vI2[3]};
            cs[3][t + 1] = float4{vJ2[0], vJ2[1], vJ2[2], vJ2[3]};
            cs[4][t + 1] = float4{vIJ[0], vIJ[1], vIJ[2], vIJ[3]};
            __syncthreads();

            float hsI[4], hsJ[4], hsI2[4], hsJ2[4], hsIJ[4];
            hslide(cs[0][t], cs[0][t + 2], vI, hsI);
            hslide(cs[1][t], cs[1][t + 2], vJ, hsJ);
            hslide(cs[2][t], cs[2][t + 2], vI2, hsI2);
            hslide(cs[3][t], cs[3][t + 2], vJ2, hsJ2);
            hslide(cs[4][t], cs[4][t + 2], vIJ, hsIJ);
            __syncthreads();   // protect LDS against next iteration's writes

#pragma unroll
            for (int c = 0; c < 4; ++c) {
                const float Is = hsI[c], Js = hsJ[c];
                const float cross = fmaf(-Is * Js, RW, hsIJ[c]);
                const float Iv = fmaf(-Is * Is, RW, hsI2[c]);
                const float Jv = fmaf(-Js * Js, RW, hsJ2[c]);
                const float den = fmaf(Iv, Jv, 1e-9f);
                ccacc += cross * cross * __builtin_amdgcn_rcpf(den);
            }

            vrow<-1>(Ib, Jb, y - 4, t, vI, vJ, vI2, vJ2, vIJ);
        }

#pragma unroll
        for (int o = 32; o; o >>= 1) ccacc += __shfl_down(ccacc, o);
        if (lane == 0) red[wid] = ccacc;
        __syncthreads();
        if (t == 0) ws[nb] = red[0] + red[1] + red[2] + red[3];
    } else {
        // ---------------- smoothness path ----------------
        const int sb = bid >> 1;                        // [0, 1024)
        const int r0 = sb * SROWS;                      // flat row in [0, 16384)
        const float* base = S + (size_t)r0 * WW;
        float dxacc = 0.f, dyacc = 0.f;

        float4 v = ((const float4*)base)[t];
#pragma unroll 2
        for (int k = 0; k < SROWS; ++k) {
            const int y = (r0 + k) & (HH - 1);
            const float* rp = base + (size_t)k * WW;
            const float d0 = v.y - v.x, d1 = v.z - v.y, d2 = v.w - v.z;
            dxacc += d0 * d0 + d1 * d1 + d2 * d2;
            if (t < 255) { const float vr = rp[4 * t + 4]; const float d3 = vr - v.w; dxacc += d3 * d3; }
            if (y < HH - 1) {
                const float4 vn = ((const float4*)(rp + WW))[t];
                const float e0 = vn.x - v.x, e1 = vn.y - v.y, e2 = vn.z - v.z, e3 = vn.w - v.w;
                dyacc += e0 * e0 + e1 * e1 + e2 * e2 + e3 * e3;
                v = vn;
            }
        }

#pragma unroll
        for (int o = 32; o; o >>= 1) {
            dxacc += __shfl_down(dxacc, o);
            dyacc += __shfl_down(dyacc, o);
        }
        if (lane == 0) { red[wid] = dxacc; red[4 + wid] = dyacc; }
        __syncthreads();
        if (t == 0) {
            ws[NCC_BLOCKS + sb] = red[0] + red[1] + red[2] + red[3];
            ws[NCC_BLOCKS + SM_BLOCKS + sb] = red[4] + red[5] + red[6] + red[7];
        }
    }
}

__global__ __launch_bounds__(256) void finalize_kernel(const float* __restrict__ ws,
                                                       float* __restrict__ out) {
    __shared__ double sd[256];
    __shared__ double res[3];
    const int t = threadIdx.x;
    double cc = 0.0, dx = 0.0, dy = 0.0;
    for (int i = t; i < NCC_BLOCKS; i += 256) cc += (double)ws[i];
    for (int i = t; i < SM_BLOCKS; i += 256) dx += (double)ws[NCC_BLOCKS + i];
    for (int i = t; i < SM_BLOCKS; i += 256) dy += (double)ws[NCC_BLOCKS + SM_BLOCKS + i];

    sd[t] = cc; __syncthreads();
    for (int s = 128; s; s >>= 1) { if (t < s) sd[t] += sd[t + s]; __syncthreads(); }
    if (t == 0) res[0] = sd[0];
    __syncthreads();
    sd[t] = dx; __syncthreads();
    for (int s = 128; s; s >>= 1) { if (t < s) sd[t] += sd[t + s]; __syncthreads(); }
    if (t == 0) res[1] = sd[0];
    __syncthreads();
    sd[t] = dy; __syncthreads();
    for (int s = 128; s; s >>= 1) { if (t < s) sd[t] += sd[t + s]; __syncthreads(); }
    if (t == 0) {
        res[2] = sd[0];
        const double ncc = -(res[0] / ((double)NB * 1.0 * HH * WW));
        const double mdx = res[1] / ((double)NB * 2.0 * HH * (WW - 1));
        const double mdy = res[2] / ((double)NB * 2.0 * (HH - 1) * WW);
        const double smooth = 0.01 * 0.5 * (mdx + mdy);
        out[0] = (float)(ncc + smooth);
        out[1] = (float)ncc;
        out[2] = (float)smooth;
    }
}

extern "C" void kernel_launch(void* const* d_in, const int* in_sizes, int n_in,
                              void* d_out, int out_size, void* d_ws, size_t ws_size,
                              hipStream_t stream) {
    const float* I = (const float*)d_in[0];
    const float* J = (const float*)d_in[1];
    const float* S = (const float*)d_in[2];
    float* ws = (float*)d_ws;     // 3072 float partials (12 KB)
    float* out = (float*)d_out;

    fused_kernel<<<NCC_BLOCKS + SM_BLOCKS, 256, 0, stream>>>(I, J, S, ws);
    finalize_kernel<<<1, 256, 0, stream>>>(ws, out);
}

// Round 4
// 175.809 us; speedup vs baseline: 1.0378x; 1.0378x over previous
//
#include <hip/hip_runtime.h>

#define HH 1024
#define WW 1024
#define NB 8
#define TY 4                            // output rows per NCC wave
#define NCC_WAVES (NB * (HH / TY))      // 2048
#define NCC_BLOCKS (NCC_WAVES / 4)      // 512
#define SM_BLOCKS 256                   // 4 waves x 16 rows = 64 rows/block
#define GRID (NCC_BLOCKS + SM_BLOCKS)   // 768: bid%3<2 -> NCC, bid%3==2 -> SM
#define RW (1.0f / 81.0f)

// Vertical sliding accumulate over 16 columns/lane. y is wave-uniform.
template <int SGN>
__device__ __forceinline__ void vrow16(const float* __restrict__ Ib, const float* __restrict__ Jb,
                                       int y, int lane,
                                       float vI[16], float vJ[16],
                                       float vI2[16], float vJ2[16], float vIJ[16]) {
    if (y < 0 || y >= HH) return;
    const float4* Ir = (const float4*)(Ib + (size_t)y * WW) + 4 * lane;
    const float4* Jr = (const float4*)(Jb + (size_t)y * WW) + 4 * lane;
    float4 i4[4], j4[4];
#pragma unroll
    for (int k = 0; k < 4; ++k) i4[k] = Ir[k];
#pragma unroll
    for (int k = 0; k < 4; ++k) j4[k] = Jr[k];
#pragma unroll
    for (int k = 0; k < 4; ++k) {
        const float fi[4] = {i4[k].x, i4[k].y, i4[k].z, i4[k].w};
        const float fj[4] = {j4[k].x, j4[k].y, j4[k].z, j4[k].w};
#pragma unroll
        for (int e = 0; e < 4; ++e) {
            const int c = 4 * k + e;
            const float a = fi[e], b = fj[e];
            if (SGN > 0) {
                vI[c] += a; vJ[c] += b;
                vI2[c] = fmaf(a, a, vI2[c]);
                vJ2[c] = fmaf(b, b, vJ2[c]);
                vIJ[c] = fmaf(a, b, vIJ[c]);
            } else {
                vI[c] -= a; vJ[c] -= b;
                vI2[c] = fmaf(-a, a, vI2[c]);
                vJ2[c] = fmaf(-b, b, vJ2[c]);
                vIJ[c] = fmaf(-a, b, vIJ[c]);
            }
        }
    }
}

__global__ __launch_bounds__(256) void fused_kernel(const float* __restrict__ I,
                                                    const float* __restrict__ J,
                                                    const float* __restrict__ S,
                                                    float* __restrict__ ws) {
    __shared__ float red[8];
    const int bid = blockIdx.x;
    const int t = threadIdx.x;
    const int lane = t & 63;
    const int wid = t >> 6;

    if ((bid % 3) < 2) {
        // ---------------- NCC: one wave = one 4-row x 1024-col strip ----------------
        const int nblk = (bid / 3) * 2 + (bid % 3);     // [0, 512)
        const int ss = nblk * 4 + wid;                  // strip id [0, 2048)
        const int b = ss >> 8;                          // image
        const int y0 = (ss & 255) * TY;
        const float* Ib = I + (size_t)b * HH * WW;
        const float* Jb = J + (size_t)b * HH * WW;

        float vI[16], vJ[16], vI2[16], vJ2[16], vIJ[16];
#pragma unroll
        for (int c = 0; c < 16; ++c) { vI[c] = 0; vJ[c] = 0; vI2[c] = 0; vJ2[c] = 0; vIJ[c] = 0; }
        float ccacc = 0.f;

        // warm-up: rows y0-4 .. y0+3
#pragma unroll
        for (int k = 0; k < 8; ++k)
            vrow16<1>(Ib, Jb, y0 - 4 + k, lane, vI, vJ, vI2, vJ2, vIJ);

#pragma unroll
        for (int k = 0; k < TY; ++k) {
            const int y = y0 + k;
            vrow16<1>(Ib, Jb, y + 4, lane, vI, vJ, vI2, vJ2, vIJ);

            // halo exchange: left lane's cols 12..15, right lane's cols 0..3
            float lI[4], lJ[4], lI2[4], lJ2[4], lIJ[4];
            float rI[4], rJ[4], rI2[4], rJ2[4], rIJ[4];
#pragma unroll
            for (int j = 0; j < 4; ++j) {
                lI[j] = __shfl_up(vI[12 + j], 1);
                lJ[j] = __shfl_up(vJ[12 + j], 1);
                lI2[j] = __shfl_up(vI2[12 + j], 1);
                lJ2[j] = __shfl_up(vJ2[12 + j], 1);
                lIJ[j] = __shfl_up(vIJ[12 + j], 1);
                rI[j] = __shfl_down(vI[j], 1);
                rJ[j] = __shfl_down(vJ[j], 1);
                rI2[j] = __shfl_down(vI2[j], 1);
                rJ2[j] = __shfl_down(vJ2[j], 1);
                rIJ[j] = __shfl_down(vIJ[j], 1);
            }
            if (lane == 0) {
#pragma unroll
                for (int j = 0; j < 4; ++j) { lI[j] = 0; lJ[j] = 0; lI2[j] = 0; lJ2[j] = 0; lIJ[j] = 0; }
            }
            if (lane == 63) {
#pragma unroll
                for (int j = 0; j < 4; ++j) { rI[j] = 0; rJ[j] = 0; rI2[j] = 0; rJ2[j] = 0; rIJ[j] = 0; }
            }

            // sliding 9-wide horizontal windows over column sums
            float wI = lI[0] + lI[1] + lI[2] + lI[3] + vI[0] + vI[1] + vI[2] + vI[3] + vI[4];
            float wJ = lJ[0] + lJ[1] + lJ[2] + lJ[3] + vJ[0] + vJ[1] + vJ[2] + vJ[3] + vJ[4];
            float wI2 = lI2[0] + lI2[1] + lI2[2] + lI2[3] + vI2[0] + vI2[1] + vI2[2] + vI2[3] + vI2[4];
            float wJ2 = lJ2[0] + lJ2[1] + lJ2[2] + lJ2[3] + vJ2[0] + vJ2[1] + vJ2[2] + vJ2[3] + vJ2[4];
            float wIJ = lIJ[0] + lIJ[1] + lIJ[2] + lIJ[3] + vIJ[0] + vIJ[1] + vIJ[2] + vIJ[3] + vIJ[4];

#pragma unroll
            for (int c = 0; c < 16; ++c) {
                if (c > 0) {
                    const float aI = (c < 12) ? vI[c + 4] : rI[c - 12];
                    const float aJ = (c < 12) ? vJ[c + 4] : rJ[c - 12];
                    const float aI2 = (c < 12) ? vI2[c + 4] : rI2[c - 12];
                    const float aJ2 = (c < 12) ? vJ2[c + 4] : rJ2[c - 12];
                    const float aIJ = (c < 12) ? vIJ[c + 4] : rIJ[c - 12];
                    const float sI = (c >= 5) ? vI[c - 5] : lI[c - 1];
                    const float sJ = (c >= 5) ? vJ[c - 5] : lJ[c - 1];
                    const float sI2 = (c >= 5) ? vI2[c - 5] : lI2[c - 1];
                    const float sJ2 = (c >= 5) ? vJ2[c - 5] : lJ2[c - 1];
                    const float sIJ = (c >= 5) ? vIJ[c - 5] : lIJ[c - 1];
                    wI += aI - sI; wJ += aJ - sJ;
                    wI2 += aI2 - sI2; wJ2 += aJ2 - sJ2;
                    wIJ += aIJ - sIJ;
                }
                const float t1 = wI * wJ;
                const float cross = fmaf(-t1, RW, wIJ);
                const float t2 = wI * wI;
                const float Iv = fmaf(-t2, RW, wI2);
                const float t3 = wJ * wJ;
                const float Jv = fmaf(-t3, RW, wJ2);
                const float den = fmaf(Iv, Jv, 1e-9f);
                ccacc += cross * cross * __builtin_amdgcn_rcpf(den);
            }

            vrow16<-1>(Ib, Jb, y - 4, lane, vI, vJ, vI2, vJ2, vIJ);
        }

#pragma unroll
        for (int o = 32; o; o >>= 1) ccacc += __shfl_down(ccacc, o);
        if (lane == 0) red[wid] = ccacc;
        __syncthreads();
        if (t == 0) ws[nblk] = red[0] + red[1] + red[2] + red[3];
    } else {
        // ---------------- smoothness: one wave = 16 rows x 1024 cols ----------------
        const int sb = bid / 3;                          // [0, 256)
        const int r0 = sb * 64 + wid * 16;               // flat row [0, 16384)
        const float* base = S + (size_t)r0 * WW;
        float dxacc = 0.f, dyacc = 0.f;

        float4 v[4];
        {
            const float4* rp4 = (const float4*)base + 4 * lane;
#pragma unroll
            for (int k = 0; k < 4; ++k) v[k] = rp4[k];
        }
#pragma unroll 2
        for (int k = 0; k < 16; ++k) {
            // dx: 15 internal diffs + 1 cross-lane (right neighbor's col0 - own col15)
            const float f[16] = {v[0].x, v[0].y, v[0].z, v[0].w, v[1].x, v[1].y, v[1].z, v[1].w,
                                 v[2].x, v[2].y, v[2].z, v[2].w, v[3].x, v[3].y, v[3].z, v[3].w};
#pragma unroll
            for (int c = 0; c < 15; ++c) { const float d = f[c + 1] - f[c]; dxacc = fmaf(d, d, dxacc); }
            const float nb0 = __shfl_down(v[0].x, 1);
            if (lane < 63) { const float d = nb0 - f[15]; dxacc = fmaf(d, d, dxacc); }

            if (((r0 + k) & (HH - 1)) != HH - 1) {
                const float4* np4 = (const float4*)(base + (size_t)(k + 1) * WW) + 4 * lane;
                float4 nv[4];
#pragma unroll
                for (int q = 0; q < 4; ++q) nv[q] = np4[q];
#pragma unroll
                for (int q = 0; q < 4; ++q) {
                    const float e0 = nv[q].x - v[q].x, e1 = nv[q].y - v[q].y;
                    const float e2 = nv[q].z - v[q].z, e3 = nv[q].w - v[q].w;
                    dyacc = fmaf(e0, e0, dyacc); dyacc = fmaf(e1, e1, dyacc);
                    dyacc = fmaf(e2, e2, dyacc); dyacc = fmaf(e3, e3, dyacc);
                }
#pragma unroll
                for (int q = 0; q < 4; ++q) v[q] = nv[q];
            }
        }

#pragma unroll
        for (int o = 32; o; o >>= 1) {
            dxacc += __shfl_down(dxacc, o);
            dyacc += __shfl_down(dyacc, o);
        }
        if (lane == 0) { red[wid] = dxacc; red[4 + wid] = dyacc; }
        __syncthreads();
        if (t == 0) {
            ws[NCC_BLOCKS + sb] = red[0] + red[1] + red[2] + red[3];
            ws[NCC_BLOCKS + SM_BLOCKS + sb] = red[4] + red[5] + red[6] + red[7];
        }
    }
}

__global__ __launch_bounds__(256) void finalize_kernel(const float* __restrict__ ws,
                                                       float* __restrict__ out) {
    __shared__ double sd[256];
    __shared__ double res[3];
    const int t = threadIdx.x;
    double cc = 0.0, dx = 0.0, dy = 0.0;
    for (int i = t; i < NCC_BLOCKS; i += 256) cc += (double)ws[i];
    for (int i = t; i < SM_BLOCKS; i += 256) dx += (double)ws[NCC_BLOCKS + i];
    for (int i = t; i < SM_BLOCKS; i += 256) dy += (double)ws[NCC_BLOCKS + SM_BLOCKS + i];

    sd[t] = cc; __syncthreads();
    for (int s = 128; s; s >>= 1) { if (t < s) sd[t] += sd[t + s]; __syncthreads(); }
    if (t == 0) res[0] = sd[0];
    __syncthreads();
    sd[t] = dx; __syncthreads();
    for (int s = 128; s; s >>= 1) { if (t < s) sd[t] += sd[t + s]; __syncthreads(); }
    if (t == 0) res[1] = sd[0];
    __syncthreads();
    sd[t] = dy; __syncthreads();
    for (int s = 128; s; s >>= 1) { if (t < s) sd[t] += sd[t + s]; __syncthreads(); }
    if (t == 0) {
        res[2] = sd[0];
        const double ncc = -(res[0] / ((double)NB * 1.0 * HH * WW));
        const double mdx = res[1] / ((double)NB * 2.0 * HH * (WW - 1));
        const double mdy = res[2] / ((double)NB * 2.0 * (HH - 1) * WW);
        const double smooth = 0.01 * 0.5 * (mdx + mdy);
        out[0] = (float)(ncc + smooth);
        out[1] = (float)ncc;
        out[2] = (float)smooth;
    }
}

extern "C" void kernel_launch(void* const* d_in, const int* in_sizes, int n_in,
                              void* d_out, int out_size, void* d_ws, size_t ws_size,
                              hipStream_t stream) {
    const float* I = (const float*)d_in[0];
    const float* J = (const float*)d_in[1];
    const float* S = (const float*)d_in[2];
    float* ws = (float*)d_ws;
    float* out = (float*)d_out;

    fused_kernel<<<GRID, 256, 0, stream>>>(I, J, S, ws);
    finalize_kernel<<<1, 256, 0, stream>>>(ws, out);
}